// Round 1
// baseline (602.740 us; speedup 1.0000x reference)
//
#include <hip/hip_runtime.h>
#include <stdint.h>

typedef short bf16x8 __attribute__((ext_vector_type(8)));
typedef float f32x4 __attribute__((ext_vector_type(4)));

#define NB    8
#define CCH   192
#define HH    128
#define WW    128
#define HP    132    // padded H (halo 2 each side)
#define WP    132    // padded W
#define NCG   24     // 192/8 channel groups
#define NTAP  26     // 25 real taps + 1 zero dummy (tap pairing for K=32)

typedef __attribute__((address_space(1))) const void gvoid;
typedef __attribute__((address_space(3))) void lvoid;

__device__ __forceinline__ unsigned short f2bf(float f) {
    union { float f; unsigned int u; } v; v.f = f;
    return (unsigned short)((v.u + 0x7fffu + ((v.u >> 16) & 1u)) >> 16);
}

// ---------------------------------------------------------------------------
// x (fp32 NCHW) -> xt bf16 [b][hp 132][cg 24][wp 132][8 ci], zero halo of 2.
// Reads coalesced along w per channel; writes 16B/thread contiguous.
// ---------------------------------------------------------------------------
__global__ __launch_bounds__(256) void convert_kernel(const float* __restrict__ x,
                                                      unsigned short* __restrict__ xt) {
    int idx = blockIdx.x * 256 + threadIdx.x;          // chunk id
    int wp = idx % WP;
    int t  = idx / WP;
    int cg = t % NCG; t /= NCG;
    int hp = t % HP;
    int b  = t / HP;
    if (b >= NB) return;
    unsigned int pk[4] = {0u, 0u, 0u, 0u};
    if (hp >= 2 && hp < HP - 2 && wp >= 2 && wp < WP - 2) {
        const float* xp = x + (((size_t)(b * CCH + cg * 8)) * HH + (hp - 2)) * WW + (wp - 2);
        #pragma unroll
        for (int j = 0; j < 4; ++j) {
            unsigned int lo = f2bf(xp[(size_t)(2 * j) * HH * WW]);
            unsigned int hi = f2bf(xp[(size_t)(2 * j + 1) * HH * WW]);
            pk[j] = lo | (hi << 16);
        }
    }
    uint4 v; v.x = pk[0]; v.y = pk[1]; v.z = pk[2]; v.w = pk[3];
    *reinterpret_cast<uint4*>(xt + (size_t)idx * 8) = v;
}

// ---------------------------------------------------------------------------
// Fold all 5 weight tensors into one effective 5x5 (26-tap) bf16 kernel.
// Output layout (elements): Wg[(((tap*12 + cib)*2 + c8)*192 + co)*8 + e]
//   where ci = cib*16 + c8*8 + e  -> A-fragment loads are contiguous per
//   16 consecutive co (lanes 0..15 of a wave).
// Block = (tap, 16-co slice), 192 threads (one per ci).
// ---------------------------------------------------------------------------
__global__ __launch_bounds__(192) void fold_kernel(const float* __restrict__ w1,
                                                   const float* __restrict__ w3,
                                                   const float* __restrict__ w5,
                                                   const float* __restrict__ wd,
                                                   const float* __restrict__ wf,
                                                   unsigned short* __restrict__ Wg) {
    int tap = blockIdx.x;          // 0..25
    int co0 = blockIdx.y * 16;     // 0..176
    int ci  = threadIdx.x;         // 0..191

    __shared__ float coefs[16][768];
    for (int i = threadIdx.x; i < 16 * 768; i += 192)
        coefs[i / 768][i % 768] = wf[(co0 + i / 768) * 768 + (i % 768)];
    __syncthreads();

    float acc[16];
    #pragma unroll
    for (int u = 0; u < 16; ++u) acc[u] = 0.f;

    if (tap < 25) {
        int ty = tap / 5, tx = tap % 5;
        bool has3 = (ty >= 1 && ty <= 3 && tx >= 1 && tx <= 3);
        bool hasd = (((ty & 1) == 0) && ((tx & 1) == 0));
        bool has1 = (tap == 12);
        for (int m = 0; m < 192; ++m) {
            float v5 = w5[((m * 192 + ci) * 5 + ty) * 5 + tx];
            #pragma unroll
            for (int u = 0; u < 16; ++u) acc[u] += coefs[u][384 + m] * v5;
            if (has3) {
                float v3 = w3[((m * 192 + ci) * 3 + (ty - 1)) * 3 + (tx - 1)];
                #pragma unroll
                for (int u = 0; u < 16; ++u) acc[u] += coefs[u][192 + m] * v3;
            }
            if (hasd) {
                float vd = wd[((m * 192 + ci) * 3 + (ty >> 1)) * 3 + (tx >> 1)];
                #pragma unroll
                for (int u = 0; u < 16; ++u) acc[u] += coefs[u][576 + m] * vd;
            }
            if (has1) {
                float v1 = w1[m * 192 + ci];
                #pragma unroll
                for (int u = 0; u < 16; ++u) acc[u] += coefs[u][m] * v1;
            }
        }
    }
    int cib = ci >> 4, c8 = (ci >> 3) & 1, e = ci & 7;
    #pragma unroll
    for (int u = 0; u < 16; ++u) {
        size_t o = ((size_t)((tap * 12 + cib) * 2 + c8) * 192 + (co0 + u)) * 8 + e;
        Wg[o] = f2bf(acc[u]);
    }
}

// ---------------------------------------------------------------------------
// Main conv: implicit GEMM, M=c_out, N=pixels, K=(tap-pair, 16 ci) -> K=32 MFMA.
// Block: 64 co x 256 px (2 output rows), 4 waves, each wave 64co x 64px
// = 4x4 MFMA 16x16 tiles. X staged in LDS via global_load_lds (width 16),
// weights direct from global (L1/L2-resident, shared by all waves).
// ---------------------------------------------------------------------------
#define LDS_CHUNKS 1792    // 1584 real (6 rows * 2 c8 * 132 px) + pad to 7*256
__global__ __launch_bounds__(256, 3) void conv_kernel(const unsigned short* __restrict__ xt,
                                                      const unsigned short* __restrict__ Wg,
                                                      float* __restrict__ out) {
    __shared__ bf16x8 xs[LDS_CHUNKS];   // 28672 B

    int tid  = threadIdx.x;
    int lane = tid & 63;
    int wid  = tid >> 6;
    int bh   = blockIdx.x;              // 0..511 : b*64 + h0/2
    int b    = bh >> 6;
    int h0   = (bh & 63) * 2;
    int co0  = blockIdx.y * 64;

    int l15   = lane & 15;
    int c8sel = (lane >> 4) & 1;
    int hsel  = lane >> 5;              // which tap of the pair
    int r_w   = wid >> 1;               // output row within pair (0/1)
    int wb    = (wid & 1) * 64 + l15;   // w base + lane

    f32x4 acc[4][4];
    #pragma unroll
    for (int m = 0; m < 4; ++m)
        #pragma unroll
        for (int n = 0; n < 4; ++n) acc[m][n] = (f32x4){0.f, 0.f, 0.f, 0.f};

    // per-lane invariants
    // A elem addr = tap*36864 + cib*3072 + c8sel*1536 + co*8  (+i in vector)
    int a_lane = c8sel * 1536 + (co0 + l15) * 8 + hsel * 36864;
    // B chunk    = ((r_w + ty)*2 + c8sel)*132 + wb + tx  (+ n*16)
    int b_lane = (r_w * 2 + c8sel) * 132 + wb;

    for (int cib = 0; cib < 12; ++cib) {
        int cg0 = cib * 2;
        // ---- stage 6 rows x 2 c8-groups x 132 px (16B chunks) ----
        #pragma unroll
        for (int it = 0; it < 7; ++it) {
            int chunk = it * 256 + tid;
            int sc = (chunk < 1584) ? chunk : 0;
            int row = sc / 264;
            int rem = sc - row * 264;
            int c8  = rem / 132;
            int p   = rem - c8 * 132;
            const unsigned short* src =
                xt + ((size_t)((b * HP + h0 + row) * NCG + (cg0 + c8)) * WP + p) * 8;
            __builtin_amdgcn_global_load_lds((gvoid*)src,
                                             (lvoid*)&xs[it * 256 + wid * 64],
                                             16, 0, 0);
        }
        __syncthreads();

        const unsigned short* wpb = Wg + (a_lane + cib * 3072);
        #pragma unroll
        for (int p = 0; p < 13; ++p) {
            const int tapA = 2 * p, tapB = 2 * p + 1;
            const int tyA = tapA / 5, txA = tapA % 5;
            const int tyB = (tapB < 25) ? tapB / 5 : 0;
            const int txB = (tapB < 25) ? tapB % 5 : 0;
            const int dA = tyA * 264 + txA;
            const int dB = tyB * 264 + txB;
            int bd = hsel ? dB : dA;

            bf16x8 a[4], bx[4];
            #pragma unroll
            for (int m = 0; m < 4; ++m)
                a[m] = *reinterpret_cast<const bf16x8*>(wpb + p * 73728 + m * 128);
            #pragma unroll
            for (int n = 0; n < 4; ++n)
                bx[n] = xs[b_lane + bd + n * 16];
            #pragma unroll
            for (int m = 0; m < 4; ++m)
                #pragma unroll
                for (int n = 0; n < 4; ++n)
                    acc[m][n] = __builtin_amdgcn_mfma_f32_16x16x32_bf16(a[m], bx[n],
                                                                        acc[m][n], 0, 0, 0);
        }
        __syncthreads();
    }

    // epilogue: D layout col(px)=lane&15, row(co)=(lane>>4)*4+reg
    int h = h0 + r_w;
    #pragma unroll
    for (int m = 0; m < 4; ++m) {
        int co = co0 + m * 16 + (lane >> 4) * 4;
        #pragma unroll
        for (int n = 0; n < 4; ++n) {
            int w = (wid & 1) * 64 + n * 16 + l15;
            float* op = out + (((size_t)(b * CCH + co)) * HH + h) * WW + w;
            #pragma unroll
            for (int j = 0; j < 4; ++j)
                op[(size_t)j * HH * WW] = acc[m][n][j];
        }
    }
}

extern "C" void kernel_launch(void* const* d_in, const int* in_sizes, int n_in,
                              void* d_out, int out_size, void* d_ws, size_t ws_size,
                              hipStream_t stream) {
    const float* x  = (const float*)d_in[0];
    const float* w1 = (const float*)d_in[1];
    const float* w3 = (const float*)d_in[2];
    const float* w5 = (const float*)d_in[3];
    const float* wd = (const float*)d_in[4];
    const float* wf = (const float*)d_in[5];
    float* out = (float*)d_out;

    unsigned short* xt = (unsigned short*)d_ws;                       // 53.5 MB
    unsigned short* Wg = xt + (size_t)NB * HP * NCG * WP * 8;         // 1.9 MB

    int conv_chunks = NB * HP * NCG * WP;                             // 3,345,408
    convert_kernel<<<conv_chunks / 256, 256, 0, stream>>>(x, xt);
    fold_kernel<<<dim3(NTAP, 12), 192, 0, stream>>>(w1, w3, w5, wd, wf, Wg);
    conv_kernel<<<dim3(512, 3), 256, 0, stream>>>(xt, Wg, out);
}

// Round 2
// 462.087 us; speedup vs baseline: 1.3044x; 1.3044x over previous
//
#include <hip/hip_runtime.h>
#include <stdint.h>

typedef short bf16x8 __attribute__((ext_vector_type(8)));
typedef float f32x4 __attribute__((ext_vector_type(4)));

#define NB    8
#define CCH   192
#define HH    128
#define WW    128
#define HP    132    // padded H (halo 2 each side)
#define WP    132    // padded W
#define NCG   24     // 192/8 channel groups
#define NSLOT 26     // 25 real taps + 1 zero dummy (tap pairing for K=32)

typedef __attribute__((address_space(1))) const void gvoid;
typedef __attribute__((address_space(3))) void lvoid;

// Tap pairing chosen so Delta = d(T[2p+1]) - d(T[2p]) has (Delta mod 8) in
// {1,2,5}: the 4 ds_read_b128 quarter-groups land at distinct 16B classes
// mod 128B -> no bank aliasing between quarters. d(t) = (t/5)*264 + t%5.
__device__ const int T_slot[26] = {0,1, 2,3, 4,6, 5,7, 8,9, 10,11, 12,13,
                                   14,16, 15,17, 18,19, 20,21, 22,23, 24,25};

__device__ __forceinline__ unsigned short f2bf(float f) {
    union { float f; unsigned int u; } v; v.f = f;
    return (unsigned short)((v.u + 0x7fffu + ((v.u >> 16) & 1u)) >> 16);
}

// ---------------------------------------------------------------------------
// x (fp32 NCHW) -> xt bf16 [b][hp 132][cg 24][wp 132][8 ci], zero halo of 2.
// ---------------------------------------------------------------------------
__global__ __launch_bounds__(256) void convert_kernel(const float* __restrict__ x,
                                                      unsigned short* __restrict__ xt) {
    int idx = blockIdx.x * 256 + threadIdx.x;          // chunk id
    int wp = idx % WP;
    int t  = idx / WP;
    int cg = t % NCG; t /= NCG;
    int hp = t % HP;
    int b  = t / HP;
    if (b >= NB) return;
    unsigned int pk[4] = {0u, 0u, 0u, 0u};
    if (hp >= 2 && hp < HP - 2 && wp >= 2 && wp < WP - 2) {
        const float* xp = x + (((size_t)(b * CCH + cg * 8)) * HH + (hp - 2)) * WW + (wp - 2);
        #pragma unroll
        for (int j = 0; j < 4; ++j) {
            unsigned int lo = f2bf(xp[(size_t)(2 * j) * HH * WW]);
            unsigned int hi = f2bf(xp[(size_t)(2 * j + 1) * HH * WW]);
            pk[j] = lo | (hi << 16);
        }
    }
    uint4 v; v.x = pk[0]; v.y = pk[1]; v.z = pk[2]; v.w = pk[3];
    *reinterpret_cast<uint4*>(xt + (size_t)idx * 8) = v;
}

// ---------------------------------------------------------------------------
// wf fp32 [192 co][768 m'] -> Abf bf16 row-major (A operand of fold GEMM)
// ---------------------------------------------------------------------------
__global__ __launch_bounds__(256) void wfconv_kernel(const float* __restrict__ wf,
                                                     unsigned short* __restrict__ Abf) {
    int i = (blockIdx.x * 256 + threadIdx.x) * 8;      // 147456 total
    float4 a = *reinterpret_cast<const float4*>(wf + i);
    float4 b = *reinterpret_cast<const float4*>(wf + i + 4);
    uint4 v;
    v.x = (unsigned int)f2bf(a.x) | ((unsigned int)f2bf(a.y) << 16);
    v.y = (unsigned int)f2bf(a.z) | ((unsigned int)f2bf(a.w) << 16);
    v.z = (unsigned int)f2bf(b.x) | ((unsigned int)f2bf(b.y) << 16);
    v.w = (unsigned int)f2bf(b.z) | ((unsigned int)f2bf(b.w) << 16);
    *reinterpret_cast<uint4*>(Abf + i) = v;
}

// ---------------------------------------------------------------------------
// Repack branch weights into fold-GEMM B operand:
//   Btp[((tap*24 + kstep)*772 + q*193 + ci)*8 + j]  (bf16), k = kstep*32+q*8+j
//   m' = k: br = k/192 (0:w1 1:w3 2:w5 3:wd), m = k - br*192.
//   Value = w_br[m][ci][tap-in-branch] or 0 if branch inactive at tap.
//   q-stride 193 chunks (not 192): quarter bases at {0,16,32,48} mod 128B.
// ---------------------------------------------------------------------------
__global__ __launch_bounds__(256) void repack_kernel(const float* __restrict__ w1,
                                                     const float* __restrict__ w3,
                                                     const float* __restrict__ w5,
                                                     const float* __restrict__ wd,
                                                     unsigned short* __restrict__ Btp) {
    int idx = blockIdx.x * 256 + threadIdx.x;          // 460800 = 25*96*192
    int ci  = idx % 192;
    int t2  = idx / 192;
    int kb  = t2 % 96;                                  // k-block of 8
    int tap = t2 / 96;                                  // 0..24 (real taps)
    int ty = tap / 5, tx = tap % 5;
    int br = kb / 24;
    int m0 = (kb % 24) * 8;

    bool active;
    const float* src;
    int stride;
    if (br == 0) {        // w1: center tap only
        active = (tap == 12);
        src = w1 + m0 * 192 + ci; stride = 192;
    } else if (br == 1) { // w3: center 3x3
        active = (ty >= 1 && ty <= 3 && tx >= 1 && tx <= 3);
        src = w3 + (size_t)(m0 * 192 + ci) * 9 + (ty - 1) * 3 + (tx - 1); stride = 192 * 9;
    } else if (br == 2) { // w5: all taps
        active = true;
        src = w5 + (size_t)(m0 * 192 + ci) * 25 + ty * 5 + tx; stride = 192 * 25;
    } else {              // wd: dilated -> even taps
        active = (((ty & 1) == 0) && ((tx & 1) == 0));
        src = wd + (size_t)(m0 * 192 + ci) * 9 + (ty >> 1) * 3 + (tx >> 1); stride = 192 * 9;
    }
    uint4 v = {0u, 0u, 0u, 0u};
    if (active) {
        unsigned int pk[4];
        #pragma unroll
        for (int j = 0; j < 4; ++j) {
            unsigned int lo = f2bf(src[(size_t)(2 * j) * stride]);
            unsigned int hi = f2bf(src[(size_t)(2 * j + 1) * stride]);
            pk[j] = lo | (hi << 16);
        }
        v.x = pk[0]; v.y = pk[1]; v.z = pk[2]; v.w = pk[3];
    }
    int ks = kb >> 2, q = kb & 3;
    size_t o = ((size_t)(tap * 24 + ks) * 772 + q * 193 + ci) * 8;
    *reinterpret_cast<uint4*>(Btp + o) = v;
}

// ---------------------------------------------------------------------------
// Fold GEMM: per slot s (26 blocks), C[co][ci] = sum_k Abf[co][k]*B_t[k][ci],
// K=768 (24 MFMA steps), tap t = T_slot[s]; write bf16 into Wg slot layout
//   Wg[(((s*12 + cib)*2 + c8)*192 + co)*8 + e],  ci = cib*16 + c8*8 + e.
// 4 waves: wave w computes co in [w*48, w*48+48) x all 192 ci.
// B staged in LDS double-buffered via global_load_lds.
// ---------------------------------------------------------------------------
__global__ __launch_bounds__(256, 1) void foldgemm_kernel(const unsigned short* __restrict__ Abf,
                                                          const unsigned short* __restrict__ Btp,
                                                          unsigned short* __restrict__ Wg) {
    __shared__ bf16x8 bs[2][772];
    int s = blockIdx.x;
    int t = T_slot[s];
    int tid = threadIdx.x, lane = tid & 63, wid = tid >> 6;

    if (t == 25) {   // dummy slot: zero weights
        uint4 z = {0u, 0u, 0u, 0u};
        for (int i = tid; i < 4608; i += 256)
            *reinterpret_cast<uint4*>(Wg + (size_t)s * 36864 + (size_t)i * 8) = z;
        return;
    }
    int l15 = lane & 15, sec = lane >> 4;

    f32x4 acc[3][12];
    #pragma unroll
    for (int mt = 0; mt < 3; ++mt)
        #pragma unroll
        for (int nt = 0; nt < 12; ++nt) acc[mt][nt] = (f32x4){0.f, 0.f, 0.f, 0.f};

    const unsigned short* bsrc = Btp + (size_t)t * 24 * 772 * 8;

    // stage kstep 0 into bs[0]
    #pragma unroll
    for (int it = 0; it < 3; ++it)
        __builtin_amdgcn_global_load_lds((gvoid*)(bsrc + (size_t)(it * 256 + tid) * 8),
                                         (lvoid*)(&bs[0][it * 256 + wid * 64]), 16, 0, 0);
    if (tid < 4)
        __builtin_amdgcn_global_load_lds((gvoid*)(bsrc + (size_t)(768 + tid) * 8),
                                         (lvoid*)(&bs[0][768]), 16, 0, 0);

    for (int ks = 0; ks < 24; ++ks) {
        __syncthreads();    // drains stage loads (vmcnt) + prev compute reads
        if (ks + 1 < 24) {
            const unsigned short* nsrc = bsrc + (size_t)(ks + 1) * 772 * 8;
            bf16x8* dst = bs[(ks + 1) & 1];
            #pragma unroll
            for (int it = 0; it < 3; ++it)
                __builtin_amdgcn_global_load_lds((gvoid*)(nsrc + (size_t)(it * 256 + tid) * 8),
                                                 (lvoid*)(dst + it * 256 + wid * 64), 16, 0, 0);
            if (tid < 4)
                __builtin_amdgcn_global_load_lds((gvoid*)(nsrc + (size_t)(768 + tid) * 8),
                                                 (lvoid*)(dst + 768), 16, 0, 0);
        }
        const bf16x8* bb = bs[ks & 1];
        bf16x8 afr[3], bfr[12];
        #pragma unroll
        for (int mt = 0; mt < 3; ++mt)
            afr[mt] = *reinterpret_cast<const bf16x8*>(
                Abf + (size_t)(wid * 48 + mt * 16 + l15) * 768 + ks * 32 + sec * 8);
        #pragma unroll
        for (int nt = 0; nt < 12; ++nt)
            bfr[nt] = bb[sec * 193 + nt * 16 + l15];
        #pragma unroll
        for (int mt = 0; mt < 3; ++mt)
            #pragma unroll
            for (int nt = 0; nt < 12; ++nt)
                acc[mt][nt] = __builtin_amdgcn_mfma_f32_16x16x32_bf16(afr[mt], bfr[nt],
                                                                      acc[mt][nt], 0, 0, 0);
    }

    // epilogue: D col(ci)=lane&15, row(co within 16)=sec*4+j
    int c8 = (l15 >> 3) & 1, e = l15 & 7;
    #pragma unroll
    for (int mt = 0; mt < 3; ++mt) {
        #pragma unroll
        for (int nt = 0; nt < 12; ++nt) {
            size_t base = ((size_t)(s * 12 + nt) * 2 + c8) * 192;
            #pragma unroll
            for (int j = 0; j < 4; ++j) {
                int co = wid * 48 + mt * 16 + sec * 4 + j;
                Wg[(base + co) * 8 + e] = f2bf(acc[mt][nt][j]);
            }
        }
    }
}

// ---------------------------------------------------------------------------
// Main conv: implicit GEMM, M=c_out, N=pixels, K=(tap-pair, 16 ci) -> K=32.
// Block: 64 co x 256 px (2 output rows), 4 waves, each 4x4 MFMA 16x16 tiles.
// ---------------------------------------------------------------------------
#define LDS_CHUNKS 1792    // 1584 real (6 rows * 2 c8 * 132 px) + pad
__global__ __launch_bounds__(256, 3) void conv_kernel(const unsigned short* __restrict__ xt,
                                                      const unsigned short* __restrict__ Wg,
                                                      float* __restrict__ out) {
    __shared__ bf16x8 xs[LDS_CHUNKS];   // 28672 B

    int tid  = threadIdx.x;
    int lane = tid & 63;
    int wid  = tid >> 6;
    int bh   = blockIdx.x;              // 0..511 : b*64 + h0/2
    int b    = bh >> 6;
    int h0   = (bh & 63) * 2;
    int co0  = blockIdx.y * 64;

    int l15   = lane & 15;
    int c8sel = (lane >> 4) & 1;
    int hsel  = lane >> 5;              // which tap of the pair
    int r_w   = wid >> 1;               // output row within pair (0/1)
    int wb    = (wid & 1) * 64 + l15;   // w base + lane

    // d-offsets (chunks) for slot taps: dA[p]=d(T[2p]), dB[p]=d(T[2p+1])
    constexpr int DA[13] = {0,2,4,264,267,528,530,532,792,795,1056,1058,1060};
    constexpr int DB[13] = {1,3,265,266,268,529,531,793,794,796,1057,1059,1061};

    f32x4 acc[4][4];
    #pragma unroll
    for (int m = 0; m < 4; ++m)
        #pragma unroll
        for (int n = 0; n < 4; ++n) acc[m][n] = (f32x4){0.f, 0.f, 0.f, 0.f};

    int a_lane = c8sel * 1536 + (co0 + l15) * 8 + hsel * 36864;
    int b_lane = (r_w * 2 + c8sel) * 132 + wb;

    for (int cib = 0; cib < 12; ++cib) {
        int cg0 = cib * 2;
        #pragma unroll
        for (int it = 0; it < 7; ++it) {
            int chunk = it * 256 + tid;
            int sc = (chunk < 1584) ? chunk : 0;
            int row = sc / 264;
            int rem = sc - row * 264;
            int c8  = rem / 132;
            int p   = rem - c8 * 132;
            const unsigned short* src =
                xt + ((size_t)((b * HP + h0 + row) * NCG + (cg0 + c8)) * WP + p) * 8;
            __builtin_amdgcn_global_load_lds((gvoid*)src,
                                             (lvoid*)&xs[it * 256 + wid * 64],
                                             16, 0, 0);
        }
        __syncthreads();

        const unsigned short* wpb = Wg + (a_lane + cib * 3072);
        #pragma unroll
        for (int p = 0; p < 13; ++p) {
            int bd = hsel ? DB[p] : DA[p];

            bf16x8 a[4], bx[4];
            #pragma unroll
            for (int m = 0; m < 4; ++m)
                a[m] = *reinterpret_cast<const bf16x8*>(wpb + p * 73728 + m * 128);
            #pragma unroll
            for (int n = 0; n < 4; ++n)
                bx[n] = xs[b_lane + bd + n * 16];
            #pragma unroll
            for (int m = 0; m < 4; ++m)
                #pragma unroll
                for (int n = 0; n < 4; ++n)
                    acc[m][n] = __builtin_amdgcn_mfma_f32_16x16x32_bf16(a[m], bx[n],
                                                                        acc[m][n], 0, 0, 0);
        }
        __syncthreads();
    }

    int h = h0 + r_w;
    #pragma unroll
    for (int m = 0; m < 4; ++m) {
        int co = co0 + m * 16 + (lane >> 4) * 4;
        #pragma unroll
        for (int n = 0; n < 4; ++n) {
            int w = (wid & 1) * 64 + n * 16 + l15;
            float* op = out + (((size_t)(b * CCH + co)) * HH + h) * WW + w;
            #pragma unroll
            for (int j = 0; j < 4; ++j)
                op[(size_t)j * HH * WW] = acc[m][n][j];
        }
    }
}

extern "C" void kernel_launch(void* const* d_in, const int* in_sizes, int n_in,
                              void* d_out, int out_size, void* d_ws, size_t ws_size,
                              hipStream_t stream) {
    const float* x  = (const float*)d_in[0];
    const float* w1 = (const float*)d_in[1];
    const float* w3 = (const float*)d_in[2];
    const float* w5 = (const float*)d_in[3];
    const float* wd = (const float*)d_in[4];
    const float* wf = (const float*)d_in[5];
    float* out = (float*)d_out;

    unsigned short* xt  = (unsigned short*)d_ws;                  // 53.5 MB
    unsigned short* Wg  = xt + (size_t)NB * HP * NCG * WP * 8;    // 1.92 MB
    unsigned short* Abf = Wg + (size_t)NSLOT * 36864;             // 0.29 MB
    unsigned short* Btp = Abf + 147456;                           // 7.4 MB

    int conv_chunks = NB * HP * NCG * WP;                         // 3,345,408
    convert_kernel<<<conv_chunks / 256, 256, 0, stream>>>(x, xt);
    wfconv_kernel<<<72, 256, 0, stream>>>(wf, Abf);
    repack_kernel<<<1800, 256, 0, stream>>>(w1, w3, w5, wd, Btp);
    foldgemm_kernel<<<NSLOT, 256, 0, stream>>>(Abf, Btp, Wg);
    conv_kernel<<<dim3(512, 3), 256, 0, stream>>>(xt, Wg, out);
}